// Round 1
// baseline (622.828 us; speedup 1.0000x reference)
//
#include <hip/hip_runtime.h>
#include <math.h>

typedef __bf16 bf16_t;
typedef __bf16 bf16x8 __attribute__((ext_vector_type(8)));
typedef float  f32x4  __attribute__((ext_vector_type(4)));

#define B_    16
#define CIN_  32
#define COUT_ 32
#define G_    8
#define CH_   256      // Cin*Gin = K channels per tap
#define H_    64
#define W_    64
#define HID_  32
#define KS_   7
#define PAD_  3
#define WP_   70       // W + 2*PAD
#define LDSS  264      // 256 + 8 pad elements -> 528B row stride -> 2-way LDS aliasing (free)

#define XP_ELEMS   ((size_t)B_ * WP_ * WP_ * CH_)            // 20,070,400
#define XP_BYTES   (XP_ELEMS * 2)                             // 40,140,800 (16B aligned)
#define W2_ELEMS   ((size_t)KS_ * KS_ * 8 * 4 * 256 * 8)      // 3,211,264

// ---------------------------------------------------------------------------
// Kernel 1: x [B,Cin,Gin,H,W] fp32 -> xPad [B, 70, 70, 256] bf16 (zero border)
// channel c = cin*8+gin == plane index (b*256+c) in source. Writes coalesced.
__global__ void repack_x(const float* __restrict__ x, bf16_t* __restrict__ xp) {
    int row = blockIdx.x;             // b*70 + y
    int b = row / WP_, y = row % WP_;
    int c = threadIdx.x;              // 0..255
    int hy = y - PAD_;
    const float* src = x + (size_t)(b * CH_ + c) * (H_ * W_);
    bf16_t* dst = xp + (size_t)row * WP_ * CH_ + c;
    bool rowok = (hy >= 0) && (hy < H_);
    for (int xx = 0; xx < WP_; ++xx) {
        int wx = xx - PAD_;
        float v = 0.0f;
        if (rowok && wx >= 0 && wx < W_) v = src[hy * W_ + wx];
        dst[(size_t)xx * CH_] = (bf16_t)v;
    }
}

// ---------------------------------------------------------------------------
// Kernel 2: SIREN -> weights in MFMA-B-swizzled bf16 layout:
//   w2[ ((tap*8 + kc)*4 + hi)*256 + n )*8 + j ]  where k = kc*32+hi*8+j = cin*8+gin,
//   n = gout*32 + cout.  One block per point (gout,gin,ky,kx).
__global__ void gen_w(const float* __restrict__ thetas,
                      const float* __restrict__ W1, const float* __restrict__ b1,
                      const float* __restrict__ W2, const float* __restrict__ b2,
                      const float* __restrict__ W3, const float* __restrict__ b3,
                      bf16_t* __restrict__ w2) {
    int p = blockIdx.x;               // ((gout*8+gin)*7+ky)*7+kx
    int kx = p % KS_; p /= KS_;
    int ky = p % KS_; p /= KS_;
    int gin = p % G_; int gout = p / G_;

    float th_o = thetas[gout], th_i = thetas[gin];
    const float TWO_PI = 6.283185307179586f;
    const float PI_F   = 3.14159265358979323846f;
    float d = fmodf(th_i - th_o, TWO_PI);
    if (d < 0.0f) d += TWO_PI;
    float ag = d / PI_F - 1.0f;
    float ct = cosf(-th_o), st = sinf(-th_o);
    float yy = (float)(ky - 3) / 3.0f;
    float xx = (float)(kx - 3) / 3.0f;
    float r0 = ct * yy - st * xx;
    float r1 = st * yy + ct * xx;
    // radius-1 grid points must be INCLUDED (matches correctly-rounded fp32 ref);
    // next radius^2 is 10/9, so 1.00001 separates cleanly.
    float mask = (r0 * r0 + r1 * r1 <= 1.00001f) ? 1.0f : 0.0f;

    float h1[HID_];
    #pragma unroll
    for (int j = 0; j < HID_; ++j) {
        float a = r0 * W1[0 * HID_ + j] + r1 * W1[1 * HID_ + j] + ag * W1[2 * HID_ + j] + b1[j];
        h1[j] = sinf(10.0f * a);
    }
    float h2[HID_];
    #pragma unroll
    for (int j = 0; j < HID_; ++j) {
        float a = b2[j];
        #pragma unroll
        for (int i = 0; i < HID_; ++i) a += h1[i] * W2[i * HID_ + j];
        h2[j] = sinf(10.0f * a);
    }
    int tap = ky * KS_ + kx;
    for (int rep = 0; rep < 4; ++rep) {
        int o = rep * 256 + threadIdx.x;      // 0..1023 = cout*32 + cin
        float a = b3[o];
        #pragma unroll
        for (int i = 0; i < HID_; ++i) a += h2[i] * W3[i * 1024 + o];
        a *= mask;
        int cout = o >> 5, cin = o & 31;
        int k = cin * G_ + gin;
        int n = gout * COUT_ + cout;
        int kc = k >> 5, hi = (k >> 3) & 3, jj = k & 7;
        w2[(((size_t)(tap * 8 + kc) * 4 + hi) * 256 + n) * 8 + jj] = (bf16_t)a;
    }
}

// ---------------------------------------------------------------------------
// Kernel 3: implicit-GEMM conv. Block = (b, h): M=64 (row of w), N=256, K=49*256.
// 4 waves, wave wv owns N-range [wv*64, wv*64+64). Per ky: stage input row
// (70x256 bf16, stride-padded) in LDS; loop kx (7) x kc (8): 16 MFMAs.
__launch_bounds__(256, 4)
__global__ void conv_mfma(const bf16_t* __restrict__ xp,
                          const bf16_t* __restrict__ w2,
                          const float* __restrict__ bias,
                          float* __restrict__ out) {
    __shared__ __align__(16) bf16_t lds[WP_ * LDSS];   // 36,960 B
    int blk = blockIdx.x;             // b*64 + h
    int b = blk >> 6, h = blk & 63;
    int tid = threadIdx.x;
    int wv = tid >> 6, lane = tid & 63;
    int lm = lane & 15, lq = lane >> 4;

    f32x4 acc[4][4];
    #pragma unroll
    for (int i = 0; i < 4; ++i)
        #pragma unroll
        for (int j = 0; j < 4; ++j) {
            f32x4 z = {0.0f, 0.0f, 0.0f, 0.0f};
            acc[i][j] = z;
        }

    for (int ky = 0; ky < KS_; ++ky) {
        __syncthreads();   // protect previous iter's LDS reads
        // stage row y = h+ky : 70*256 bf16 = 2240 chunks of 16B
        const bf16_t* src = xp + ((size_t)(b * WP_) + (h + ky)) * WP_ * CH_;
        for (int i = tid; i < WP_ * CH_ / 8; i += 256) {
            int xr = i >> 5;                 // x position 0..69
            int c0 = (i & 31) << 3;          // channel 0..248
            bf16x8 v = *reinterpret_cast<const bf16x8*>(src + (size_t)i * 8);
            *reinterpret_cast<bf16x8*>(&lds[xr * LDSS + c0]) = v;
        }
        __syncthreads();

        #pragma unroll 1
        for (int kx = 0; kx < KS_; ++kx) {
            int tap = ky * KS_ + kx;
            // B base: ((tap*32 + kc*4 + lq)*256 + n)*8, n = wv*64 + nt*16 + lm
            const bf16_t* wbase = w2 + ((size_t)(tap * 32 + lq) * 256 + (wv * 64 + lm)) * 8;
            #pragma unroll 1
            for (int kc = 0; kc < 8; ++kc) {
                const bf16_t* wp = wbase + (size_t)kc * (4 * 256 * 8);
                bf16x8 bfrag[4];
                #pragma unroll
                for (int nt = 0; nt < 4; ++nt)
                    bfrag[nt] = *reinterpret_cast<const bf16x8*>(wp + nt * (16 * 8));
                bf16x8 afrag[4];
                #pragma unroll
                for (int mt = 0; mt < 4; ++mt) {
                    int xr = mt * 16 + lm + kx;
                    afrag[mt] = *reinterpret_cast<const bf16x8*>(&lds[xr * LDSS + kc * 32 + lq * 8]);
                }
                #pragma unroll
                for (int mt = 0; mt < 4; ++mt)
                    #pragma unroll
                    for (int nt = 0; nt < 4; ++nt)
                        acc[mt][nt] = __builtin_amdgcn_mfma_f32_16x16x32_bf16(
                            afrag[mt], bfrag[nt], acc[mt][nt], 0, 0, 0);
            }
        }
    }

    // epilogue: D row = lq*4 + reg (= w offset), col = lm (= n offset)
    #pragma unroll
    for (int mt = 0; mt < 4; ++mt) {
        int wq = mt * 16 + lq * 4;
        #pragma unroll
        for (int nt = 0; nt < 4; ++nt) {
            int n = wv * 64 + nt * 16 + lm;
            int gout = n >> 5, cout = n & 31;
            float bv = bias[cout];
            f32x4 v = acc[mt][nt];
            v[0] += bv; v[1] += bv; v[2] += bv; v[3] += bv;
            float* po = out + (((size_t)(b * COUT_ + cout) * G_ + gout) * (H_ * W_)
                               + h * W_ + wq);
            *reinterpret_cast<f32x4*>(po) = v;
        }
    }
}

// ---------------------------------------------------------------------------
extern "C" void kernel_launch(void* const* d_in, const int* in_sizes, int n_in,
                              void* d_out, int out_size, void* d_ws, size_t ws_size,
                              hipStream_t stream) {
    const float* x      = (const float*)d_in[0];
    const float* thetas = (const float*)d_in[1];
    const float* W1     = (const float*)d_in[2];
    const float* b1     = (const float*)d_in[3];
    const float* W2     = (const float*)d_in[4];
    const float* b2     = (const float*)d_in[5];
    const float* W3     = (const float*)d_in[6];
    const float* b3     = (const float*)d_in[7];
    const float* bias   = (const float*)d_in[8];
    float* out = (float*)d_out;

    bf16_t* xp = (bf16_t*)d_ws;
    bf16_t* w2 = (bf16_t*)((char*)d_ws + XP_BYTES);

    hipLaunchKernelGGL(repack_x, dim3(B_ * WP_), dim3(256), 0, stream, x, xp);
    hipLaunchKernelGGL(gen_w, dim3(G_ * G_ * KS_ * KS_), dim3(256), 0, stream,
                       thetas, W1, b1, W2, b2, W3, b3, w2);
    hipLaunchKernelGGL(conv_mfma, dim3(B_ * H_), dim3(256), 0, stream,
                       xp, w2, bias, out);
}

// Round 2
// 590.231 us; speedup vs baseline: 1.0552x; 1.0552x over previous
//
#include <hip/hip_runtime.h>
#include <math.h>

typedef __bf16 bf16_t;
typedef __bf16 bf16x8 __attribute__((ext_vector_type(8)));
typedef float  f32x4  __attribute__((ext_vector_type(4)));

#define B_    16
#define CIN_  32
#define COUT_ 32
#define G_    8
#define CH_   256      // Cin*Gin = K channels per tap
#define H_    64
#define W_    64
#define HID_  32
#define KS_   7
#define PAD_  3
#define WP_   70       // W + 2*PAD
#define LDSS  264      // 256 + 8 pad elements -> 528B row stride

#define XP_ELEMS   ((size_t)B_ * WP_ * WP_ * CH_)            // 20,070,400
#define XP_BYTES   (XP_ELEMS * 2)                             // 40,140,800 (16B aligned)

#define REPACK_BLOCKS (B_ * (H_ + 6))                         // 1120: 64 interior + 6 zero rows per b
#define GENW_BLOCKS   (G_ * G_ * KS_ * KS_)                   // 3136

static __device__ __forceinline__ unsigned pack_bf16(float a, float b) {
    union { __bf16 h; unsigned short u; } ua, ub;
    ua.h = (__bf16)a; ub.h = (__bf16)b;
    return (unsigned)ua.u | ((unsigned)ub.u << 16);
}

// ---------------------------------------------------------------------------
// Fused kernel 1: blocks [0,1120): repack x fp32 [B,256,H,W] -> bf16 xPad
// [B,70,70,256] via in-register 8x8 shfl transpose (borders zeroed).
// Blocks [1120, 1120+3136): SIREN weight-gen into MFMA-B-swizzled layout.
__global__ void prep(const float* __restrict__ x, bf16_t* __restrict__ xp,
                     const float* __restrict__ thetas,
                     const float* __restrict__ W1, const float* __restrict__ b1,
                     const float* __restrict__ W2, const float* __restrict__ b2,
                     const float* __restrict__ W3, const float* __restrict__ b3,
                     bf16_t* __restrict__ w2out) {
    int tid = threadIdx.x;
    if (blockIdx.x < REPACK_BLOCKS) {
        // ---------------- repack path ----------------
        int blk = blockIdx.x;
        int b = blk / (H_ + 6), hy = blk % (H_ + 6);
        const int4 z4 = make_int4(0, 0, 0, 0);
        if (hy >= H_) {
            // zero border row: y in {0,1,2,67,68,69}
            int idx = hy - H_;
            int y = (idx < 3) ? idx : idx + 64;   // 0,1,2,67,68,69
            bf16_t* dst = xp + ((size_t)(b * WP_) + y) * WP_ * CH_;
            for (int i = tid; i < WP_ * CH_ / 8; i += 256)
                *reinterpret_cast<int4*>(dst + (size_t)i * 8) = z4;
            return;
        }
        int lane = tid & 63, wv = tid >> 6;
        int r = lane >> 3;          // row-within-tile (c offset) / col-within-tile after T
        int t = lane & 7;           // w-chunk (tile id within wave)
        size_t orow = ((size_t)(b * WP_) + (hy + 3)) * WP_ * CH_;
        // interior: 8 c-rows per wave-iter, all 64 w
        for (int it = 0; it < 8; ++it) {
            int c0 = wv * 8 + it * 32;
            const float* src = x + ((size_t)(b * CH_ + c0 + r)) * (H_ * W_)
                                 + (size_t)hy * W_ + t * 8;
            float4 f0 = *reinterpret_cast<const float4*>(src);
            float4 f1 = *reinterpret_cast<const float4*>(src + 4);
            int d0 = (int)pack_bf16(f0.x, f0.y);
            int d1 = (int)pack_bf16(f0.z, f0.w);
            int d2 = (int)pack_bf16(f1.x, f1.y);
            int d3 = (int)pack_bf16(f1.z, f1.w);
            // 8x8 transpose across lanes sharing t (r lives in lane bits 3..5)
            int p0, p1, p2, p3;
            p0 = __shfl_xor(d0, 32); p1 = __shfl_xor(d1, 32);
            p2 = __shfl_xor(d2, 32); p3 = __shfl_xor(d3, 32);
            if ((r & 4) == 0) { d2 = p0; d3 = p1; } else { d0 = p2; d1 = p3; }
            p0 = __shfl_xor(d0, 16); p1 = __shfl_xor(d1, 16);
            p2 = __shfl_xor(d2, 16); p3 = __shfl_xor(d3, 16);
            if ((r & 2) == 0) { d1 = p0; d3 = p2; } else { d0 = p1; d2 = p3; }
            p0 = __shfl_xor(d0, 8); p1 = __shfl_xor(d1, 8);
            p2 = __shfl_xor(d2, 8); p3 = __shfl_xor(d3, 8);
            if ((r & 1) == 0) {
                d0 = (d0 & 0xFFFF) | (p0 << 16);
                d1 = (d1 & 0xFFFF) | (p1 << 16);
                d2 = (d2 & 0xFFFF) | (p2 << 16);
                d3 = (d3 & 0xFFFF) | (p3 << 16);
            } else {
                d0 = (d0 & 0xFFFF0000) | ((unsigned)p0 >> 16);
                d1 = (d1 & 0xFFFF0000) | ((unsigned)p1 >> 16);
                d2 = (d2 & 0xFFFF0000) | ((unsigned)p2 >> 16);
                d3 = (d3 & 0xFFFF0000) | ((unsigned)p3 >> 16);
            }
            // lane now holds w-col = t*8+r, c = c0..c0+7
            int w = t * 8 + r;
            int4 v = make_int4(d0, d1, d2, d3);
            *reinterpret_cast<int4*>(xp + orow + (size_t)(w + 3) * CH_ + c0) = v;
        }
        // zero w-border cols {0,1,2,67,68,69} of this row
        if (tid < 192) {
            int col = tid >> 5, cg = tid & 31;
            int xx = (col < 3) ? col : col + 64;
            *reinterpret_cast<int4*>(xp + orow + (size_t)xx * CH_ + cg * 8) = z4;
        }
        return;
    }
    // ---------------- gen_w path ----------------
    int p = blockIdx.x - REPACK_BLOCKS;       // ((gout*8+gin)*7+ky)*7+kx
    int kx = p % KS_; p /= KS_;
    int ky = p % KS_; p /= KS_;
    int gin = p % G_; int gout = p / G_;

    float th_o = thetas[gout], th_i = thetas[gin];
    const float TWO_PI = 6.283185307179586f;
    const float PI_F   = 3.14159265358979323846f;
    float d = fmodf(th_i - th_o, TWO_PI);
    if (d < 0.0f) d += TWO_PI;
    float ag = d / PI_F - 1.0f;
    float ct = cosf(-th_o), st = sinf(-th_o);
    float yy = (float)(ky - 3) / 3.0f;
    float xx = (float)(kx - 3) / 3.0f;
    float r0 = ct * yy - st * xx;
    float r1 = st * yy + ct * xx;
    // radius-1 grid points are INCLUDED by the fp32 reference; next r^2 = 10/9
    float mask = (r0 * r0 + r1 * r1 <= 1.00001f) ? 1.0f : 0.0f;

    float h1[HID_];
    #pragma unroll
    for (int j = 0; j < HID_; ++j) {
        float a = r0 * W1[0 * HID_ + j] + r1 * W1[1 * HID_ + j] + ag * W1[2 * HID_ + j] + b1[j];
        h1[j] = sinf(10.0f * a);
    }
    float h2[HID_];
    #pragma unroll
    for (int j = 0; j < HID_; ++j) {
        float a = b2[j];
        #pragma unroll
        for (int i = 0; i < HID_; ++i) a += h1[i] * W2[i * HID_ + j];
        h2[j] = sinf(10.0f * a);
    }
    int tap = ky * KS_ + kx;
    for (int rep = 0; rep < 4; ++rep) {
        int o = rep * 256 + tid;              // cout*32 + cin
        float a = b3[o];
        #pragma unroll
        for (int i = 0; i < HID_; ++i) a += h2[i] * W3[i * 1024 + o];
        a *= mask;
        int cout = o >> 5, cin = o & 31;
        int k = cin * G_ + gin;
        int n = gout * COUT_ + cout;
        int kc = k >> 5, hi = (k >> 3) & 3, jj = k & 7;
        w2out[(((size_t)(tap * 8 + kc) * 4 + hi) * 256 + n) * 8 + jj] = (bf16_t)a;
    }
}

// ---------------------------------------------------------------------------
// Kernel 2: implicit-GEMM conv. Block = (b, h): M=64 spatial, N=256, K=49*256.
// Register double-buffer on B-fragments: kc+1 loads issue before kc's MFMAs.
__launch_bounds__(256, 4)
__global__ void conv_mfma(const bf16_t* __restrict__ xp,
                          const bf16_t* __restrict__ w2,
                          const float* __restrict__ bias,
                          float* __restrict__ out) {
    __shared__ __align__(16) bf16_t lds[WP_ * LDSS];   // 36,960 B
    int blk = blockIdx.x;             // b*64 + h
    int b = blk >> 6, h = blk & 63;
    int tid = threadIdx.x;
    int wv = tid >> 6, lane = tid & 63;
    int lm = lane & 15, lq = lane >> 4;

    f32x4 acc[4][4];
    #pragma unroll
    for (int i = 0; i < 4; ++i)
        #pragma unroll
        for (int j = 0; j < 4; ++j) {
            f32x4 z = {0.0f, 0.0f, 0.0f, 0.0f};
            acc[i][j] = z;
        }

    for (int ky = 0; ky < KS_; ++ky) {
        __syncthreads();   // protect previous iter's LDS reads
        const bf16_t* src = xp + ((size_t)(b * WP_) + (h + ky)) * WP_ * CH_;
        for (int i = tid; i < WP_ * CH_ / 8; i += 256) {
            int xr = i >> 5;
            int c0 = (i & 31) << 3;
            bf16x8 v = *reinterpret_cast<const bf16x8*>(src + (size_t)i * 8);
            *reinterpret_cast<bf16x8*>(&lds[xr * LDSS + c0]) = v;
        }
        __syncthreads();

        #pragma unroll 1
        for (int kx = 0; kx < KS_; ++kx) {
            int tap = ky * KS_ + kx;
            const bf16_t* wbase = w2 + ((size_t)(tap * 32 + lq) * 256 + (wv * 64 + lm)) * 8;
            bf16x8 bcur[4];
            #pragma unroll
            for (int nt = 0; nt < 4; ++nt)
                bcur[nt] = *reinterpret_cast<const bf16x8*>(wbase + nt * (16 * 8));
            #pragma unroll 1
            for (int kc = 0; kc < 8; ++kc) {
                // prefetch next kc's B-frags (last iter re-reads kc=7: harmless)
                int kcn = (kc < 7) ? kc + 1 : 7;
                const bf16_t* wpn = wbase + (size_t)kcn * (4 * 256 * 8);
                bf16x8 bnx[4];
                #pragma unroll
                for (int nt = 0; nt < 4; ++nt)
                    bnx[nt] = *reinterpret_cast<const bf16x8*>(wpn + nt * (16 * 8));
                bf16x8 afrag[4];
                #pragma unroll
                for (int mt = 0; mt < 4; ++mt) {
                    int xr = mt * 16 + lm + kx;
                    afrag[mt] = *reinterpret_cast<const bf16x8*>(&lds[xr * LDSS + kc * 32 + lq * 8]);
                }
                #pragma unroll
                for (int mt = 0; mt < 4; ++mt)
                    #pragma unroll
                    for (int nt = 0; nt < 4; ++nt)
                        acc[mt][nt] = __builtin_amdgcn_mfma_f32_16x16x32_bf16(
                            afrag[mt], bcur[nt], acc[mt][nt], 0, 0, 0);
                #pragma unroll
                for (int nt = 0; nt < 4; ++nt) bcur[nt] = bnx[nt];
            }
        }
    }

    // epilogue: D row = lq*4 + reg (= w offset), col = lm (= n offset)
    #pragma unroll
    for (int mt = 0; mt < 4; ++mt) {
        int wq = mt * 16 + lq * 4;
        #pragma unroll
        for (int nt = 0; nt < 4; ++nt) {
            int n = wv * 64 + nt * 16 + lm;
            int gout = n >> 5, cout = n & 31;
            float bv = bias[cout];
            f32x4 v = acc[mt][nt];
            v[0] += bv; v[1] += bv; v[2] += bv; v[3] += bv;
            float* po = out + (((size_t)(b * COUT_ + cout) * G_ + gout) * (H_ * W_)
                               + h * W_ + wq);
            *reinterpret_cast<f32x4*>(po) = v;
        }
    }
}

// ---------------------------------------------------------------------------
extern "C" void kernel_launch(void* const* d_in, const int* in_sizes, int n_in,
                              void* d_out, int out_size, void* d_ws, size_t ws_size,
                              hipStream_t stream) {
    const float* x      = (const float*)d_in[0];
    const float* thetas = (const float*)d_in[1];
    const float* W1     = (const float*)d_in[2];
    const float* b1     = (const float*)d_in[3];
    const float* W2     = (const float*)d_in[4];
    const float* b2     = (const float*)d_in[5];
    const float* W3     = (const float*)d_in[6];
    const float* b3     = (const float*)d_in[7];
    const float* bias   = (const float*)d_in[8];
    float* out = (float*)d_out;

    bf16_t* xp = (bf16_t*)d_ws;
    bf16_t* w2 = (bf16_t*)((char*)d_ws + XP_BYTES);

    hipLaunchKernelGGL(prep, dim3(REPACK_BLOCKS + GENW_BLOCKS), dim3(256), 0, stream,
                       x, xp, thetas, W1, b1, W2, b2, W3, b3, w2);
    hipLaunchKernelGGL(conv_mfma, dim3(B_ * H_), dim3(256), 0, stream,
                       xp, w2, bias, out);
}

// Round 3
// 518.305 us; speedup vs baseline: 1.2017x; 1.1388x over previous
//
#include <hip/hip_runtime.h>
#include <math.h>

typedef __bf16 bf16_t;
typedef __bf16 bf16x8 __attribute__((ext_vector_type(8)));
typedef float  f32x4  __attribute__((ext_vector_type(4)));

#define B_    16
#define CIN_  32
#define COUT_ 32
#define G_    8
#define CH_   256      // Cin*Gin = K channels per tap
#define H_    64
#define W_    64
#define HID_  32
#define KS_   7
#define PAD_  3
#define WP_   70       // W + 2*PAD

// xp layout: [B][y(70)][x(70)][256ch], where within each (y,x) the 32 16B
// channel-chunks are stored XOR-swizzled: chunk c16 lives at position
// c16 ^ (x & 7).  This makes the row image directly DMA-able into LDS with
// global_load_lds (contiguous, no padding) while keeping A-fragment
// ds_read_b128 at worst 2-way bank-aliased (free).
#define XP_ELEMS   ((size_t)B_ * WP_ * WP_ * CH_)            // 20,070,400
#define XP_BYTES   (XP_ELEMS * 2)                             // 40,140,800

#define REPACK_BLOCKS (B_ * (H_ + 6))                         // 1120
#define GENW_BLOCKS   (G_ * G_)                               // 64

static __device__ __forceinline__ unsigned pack_bf16(float a, float b) {
    union { __bf16 h; unsigned short u; } ua, ub;
    ua.h = (__bf16)a; ub.h = (__bf16)b;
    return (unsigned)ua.u | ((unsigned)ub.u << 16);
}

static __device__ __forceinline__ void dma16(const bf16_t* g, bf16_t* l) {
    __builtin_amdgcn_global_load_lds(
        (const __attribute__((address_space(1))) void*)g,
        (__attribute__((address_space(3))) void*)l, 16, 0, 0);
}

// ---------------------------------------------------------------------------
// Fused prep: blocks [0,1120) repack x -> swizzled bf16 xPad; blocks
// [1120,1184) = (gout,gin) SIREN weight-gen with W3 register reuse.
__global__ void prep(const float* __restrict__ x, bf16_t* __restrict__ xp,
                     const float* __restrict__ thetas,
                     const float* __restrict__ W1, const float* __restrict__ b1,
                     const float* __restrict__ W2, const float* __restrict__ b2,
                     const float* __restrict__ W3, const float* __restrict__ b3,
                     bf16_t* __restrict__ w2out) {
    __shared__ float h1s[49][33];
    __shared__ float h2s[49][33];
    __shared__ float masks[49];
    int tid = threadIdx.x;
    if (blockIdx.x < REPACK_BLOCKS) {
        // ---------------- repack path ----------------
        int blk = blockIdx.x;
        int b = blk / (H_ + 6), hy = blk % (H_ + 6);
        const int4 z4 = make_int4(0, 0, 0, 0);
        if (hy >= H_) {
            int idx = hy - H_;
            int y = (idx < 3) ? idx : idx + 64;   // 0,1,2,67,68,69
            bf16_t* dst = xp + ((size_t)(b * WP_) + y) * WP_ * CH_;
            for (int i = tid; i < WP_ * CH_ / 8; i += 256)
                *reinterpret_cast<int4*>(dst + (size_t)i * 8) = z4;
            return;
        }
        int lane = tid & 63, wv = tid >> 6;
        int r = lane >> 3;          // channel offset within tile / w offset after T
        int t = lane & 7;           // w-chunk
        size_t orow = ((size_t)(b * WP_) + (hy + 3)) * WP_ * CH_;
        for (int it = 0; it < 8; ++it) {
            int c0 = wv * 8 + it * 32;
            const float* src = x + ((size_t)(b * CH_ + c0 + r)) * (H_ * W_)
                                 + (size_t)hy * W_ + t * 8;
            float4 f0 = *reinterpret_cast<const float4*>(src);
            float4 f1 = *reinterpret_cast<const float4*>(src + 4);
            int d0 = (int)pack_bf16(f0.x, f0.y);
            int d1 = (int)pack_bf16(f0.z, f0.w);
            int d2 = (int)pack_bf16(f1.x, f1.y);
            int d3 = (int)pack_bf16(f1.z, f1.w);
            int p0, p1, p2, p3;
            p0 = __shfl_xor(d0, 32); p1 = __shfl_xor(d1, 32);
            p2 = __shfl_xor(d2, 32); p3 = __shfl_xor(d3, 32);
            if ((r & 4) == 0) { d2 = p0; d3 = p1; } else { d0 = p2; d1 = p3; }
            p0 = __shfl_xor(d0, 16); p1 = __shfl_xor(d1, 16);
            p2 = __shfl_xor(d2, 16); p3 = __shfl_xor(d3, 16);
            if ((r & 2) == 0) { d1 = p0; d3 = p2; } else { d0 = p1; d2 = p3; }
            p0 = __shfl_xor(d0, 8); p1 = __shfl_xor(d1, 8);
            p2 = __shfl_xor(d2, 8); p3 = __shfl_xor(d3, 8);
            if ((r & 1) == 0) {
                d0 = (d0 & 0xFFFF) | (p0 << 16);
                d1 = (d1 & 0xFFFF) | (p1 << 16);
                d2 = (d2 & 0xFFFF) | (p2 << 16);
                d3 = (d3 & 0xFFFF) | (p3 << 16);
            } else {
                d0 = (d0 & 0xFFFF0000) | ((unsigned)p0 >> 16);
                d1 = (d1 & 0xFFFF0000) | ((unsigned)p1 >> 16);
                d2 = (d2 & 0xFFFF0000) | ((unsigned)p2 >> 16);
                d3 = (d3 & 0xFFFF0000) | ((unsigned)p3 >> 16);
            }
            int xpos = t * 8 + r + 3;
            int c16 = c0 >> 3;
            int pp = c16 ^ (xpos & 7);       // swizzled chunk position
            int4 v = make_int4(d0, d1, d2, d3);
            *reinterpret_cast<int4*>(xp + orow + (size_t)xpos * CH_ + pp * 8) = v;
        }
        if (tid < 192) {   // zero w-border cols {0,1,2,67,68,69}
            int col = tid >> 5, cg = tid & 31;
            int xx = (col < 3) ? col : col + 64;
            *reinterpret_cast<int4*>(xp + orow + (size_t)xx * CH_ + cg * 8) = z4;
        }
        return;
    }
    // ---------------- gen_w path: block = (gout, gin) ----------------
    int blk = blockIdx.x - REPACK_BLOCKS;
    int gin = blk & 7, gout = blk >> 3;
    const float TWO_PI = 6.283185307179586f;
    const float PI_F   = 3.14159265358979323846f;
    float th_o = thetas[gout], th_i = thetas[gin];
    float d = fmodf(th_i - th_o, TWO_PI);
    if (d < 0.0f) d += TWO_PI;
    float ag = d / PI_F - 1.0f;
    float ct = cosf(-th_o), st = sinf(-th_o);

    if (tid < 196) {
        int p = tid >> 2, q = tid & 3;       // tap, j-octet
        int ky = p / 7, kx = p % 7;
        float yy = (float)(ky - 3) / 3.0f;
        float xx = (float)(kx - 3) / 3.0f;
        float r0 = ct * yy - st * xx;
        float r1 = st * yy + ct * xx;
        if (q == 0)   // radius-1 points INCLUDED (fp32 ref); next r^2 = 10/9
            masks[p] = (r0 * r0 + r1 * r1 <= 1.00001f) ? 1.0f : 0.0f;
        #pragma unroll
        for (int jo = 0; jo < 8; ++jo) {
            int j = q * 8 + jo;
            float a = r0 * W1[j] + r1 * W1[32 + j] + ag * W1[64 + j] + b1[j];
            h1s[p][j] = __sinf(10.0f * a);
        }
    }
    __syncthreads();
    if (tid < 196) {
        int p = tid >> 2, q = tid & 3;
        #pragma unroll
        for (int jo = 0; jo < 8; ++jo) {
            int j = q * 8 + jo;
            float a = b2[j];
            #pragma unroll
            for (int i = 0; i < HID_; ++i) a += h1s[p][i] * W2[i * HID_ + j];
            h2s[p][j] = __sinf(10.0f * a);
        }
    }
    __syncthreads();
    for (int rep = 0; rep < 4; ++rep) {
        int o = rep * 256 + tid;             // cout*32 + cin
        float w3c[HID_];
        #pragma unroll
        for (int i = 0; i < HID_; ++i) w3c[i] = W3[i * 1024 + o];
        float bb = b3[o];
        int cout = o >> 5, cin = o & 31;
        int k = cin * G_ + gin;
        int n = gout * COUT_ + cout;
        int kc = k >> 5, hi = (k >> 3) & 3, jj = k & 7;
        bf16_t* dst = w2out + (((size_t)kc * 4 + hi) * 256 + n) * 8 + jj;
        for (int p = 0; p < 49; ++p) {
            float a = bb;
            #pragma unroll
            for (int i = 0; i < HID_; ++i) a += h2s[p][i] * w3c[i];
            a *= masks[p];
            dst[(size_t)p * (8 * 4 * 256 * 8)] = (bf16_t)a;
        }
    }
}

// ---------------------------------------------------------------------------
// Conv: implicit GEMM, block = (b,h): M=64 spatial, N=256, K=49*256.
// Staging via global_load_lds DMA (no VGPR roundtrip, no ds_write issue);
// xp rows are pre-swizzled so the linear DMA image is the conflict-free
// LDS layout.
__launch_bounds__(256, 4)
__global__ void conv_mfma(const bf16_t* __restrict__ xp,
                          const bf16_t* __restrict__ w2,
                          const float* __restrict__ bias,
                          float* __restrict__ out) {
    __shared__ __align__(16) bf16_t lds[WP_ * CH_];   // 35,840 B, no pad
    int blk = blockIdx.x;             // b*64 + h
    int b = blk >> 6, h = blk & 63;
    int tid = threadIdx.x;
    int wv = tid >> 6, lane = tid & 63;
    int lm = lane & 15, lq = lane >> 4;

    f32x4 acc[4][4];
    #pragma unroll
    for (int i = 0; i < 4; ++i)
        #pragma unroll
        for (int j = 0; j < 4; ++j) {
            f32x4 z = {0.0f, 0.0f, 0.0f, 0.0f};
            acc[i][j] = z;
        }

    for (int ky = 0; ky < KS_; ++ky) {
        __syncthreads();   // protect previous iter's LDS reads
        // DMA one xp row (70*256 bf16 = 35840 B) in 35 wave-chunks of 1024 B
        const bf16_t* src = xp + ((size_t)(b * WP_) + (h + ky)) * WP_ * CH_;
        for (int c = wv; c < 35; c += 4)
            dma16(src + (size_t)c * 512 + lane * 8, lds + c * 512);
        __syncthreads();   // drains vmcnt(0): DMA complete

        #pragma unroll 1
        for (int kx = 0; kx < KS_; ++kx) {
            int tap = ky * KS_ + kx;
            const bf16_t* wbase = w2 + ((size_t)(tap * 32 + lq) * 256 + (wv * 64 + lm)) * 8;
            #pragma unroll 1
            for (int kc = 0; kc < 8; ++kc) {
                const bf16_t* wp = wbase + (size_t)kc * (4 * 256 * 8);
                bf16x8 bfrag[4];
                #pragma unroll
                for (int nt = 0; nt < 4; ++nt)
                    bfrag[nt] = *reinterpret_cast<const bf16x8*>(wp + nt * (16 * 8));
                bf16x8 afrag[4];
                #pragma unroll
                for (int mt = 0; mt < 4; ++mt) {
                    int xr = mt * 16 + lm + kx;
                    int pp = (kc * 4 + lq) ^ (xr & 7);   // un-swizzle
                    afrag[mt] = *reinterpret_cast<const bf16x8*>(&lds[xr * CH_ + pp * 8]);
                }
                #pragma unroll
                for (int mt = 0; mt < 4; ++mt)
                    #pragma unroll
                    for (int nt = 0; nt < 4; ++nt)
                        acc[mt][nt] = __builtin_amdgcn_mfma_f32_16x16x32_bf16(
                            afrag[mt], bfrag[nt], acc[mt][nt], 0, 0, 0);
            }
        }
    }

    // epilogue: D row = lq*4 + reg (w offset), col = lm (n offset)
    #pragma unroll
    for (int mt = 0; mt < 4; ++mt) {
        int wq = mt * 16 + lq * 4;
        #pragma unroll
        for (int nt = 0; nt < 4; ++nt) {
            int n = wv * 64 + nt * 16 + lm;
            int gout = n >> 5, cout = n & 31;
            float bv = bias[cout];
            f32x4 v = acc[mt][nt];
            v[0] += bv; v[1] += bv; v[2] += bv; v[3] += bv;
            float* po = out + (((size_t)(b * COUT_ + cout) * G_ + gout) * (H_ * W_)
                               + h * W_ + wq);
            *reinterpret_cast<f32x4*>(po) = v;
        }
    }
}

// ---------------------------------------------------------------------------
extern "C" void kernel_launch(void* const* d_in, const int* in_sizes, int n_in,
                              void* d_out, int out_size, void* d_ws, size_t ws_size,
                              hipStream_t stream) {
    const float* x      = (const float*)d_in[0];
    const float* thetas = (const float*)d_in[1];
    const float* W1     = (const float*)d_in[2];
    const float* b1     = (const float*)d_in[3];
    const float* W2     = (const float*)d_in[4];
    const float* b2     = (const float*)d_in[5];
    const float* W3     = (const float*)d_in[6];
    const float* b3     = (const float*)d_in[7];
    const float* bias   = (const float*)d_in[8];
    float* out = (float*)d_out;

    bf16_t* xp = (bf16_t*)d_ws;
    bf16_t* w2 = (bf16_t*)((char*)d_ws + XP_BYTES);

    hipLaunchKernelGGL(prep, dim3(REPACK_BLOCKS + GENW_BLOCKS), dim3(256), 0, stream,
                       x, xp, thetas, W1, b1, W2, b2, W3, b3, w2);
    hipLaunchKernelGGL(conv_mfma, dim3(B_ * H_), dim3(256), 0, stream,
                       xp, w2, bias, out);
}

// Round 4
// 499.956 us; speedup vs baseline: 1.2458x; 1.0367x over previous
//
#include <hip/hip_runtime.h>
#include <math.h>

typedef __bf16 bf16_t;
typedef __bf16 bf16x8 __attribute__((ext_vector_type(8)));
typedef float  f32x4  __attribute__((ext_vector_type(4)));

#define B_    16
#define CIN_  32
#define COUT_ 32
#define G_    8
#define CH_   256      // Cin*Gin = K channels per tap
#define H_    64
#define W_    64
#define HID_  32
#define KS_   7
#define PAD_  3
#define WP_   70       // W + 2*PAD

// xp layout: [B][y(70)][x(70)][256ch]; within each (y,x) the 32 16B channel
// chunks are XOR-swizzled (chunk c16 at position c16 ^ (x&7)) so the linear
// row image is DMA-able into LDS while A-frag ds_read_b128 stays <=2-way
// bank-aliased (free).
#define XP_ELEMS   ((size_t)B_ * WP_ * WP_ * CH_)            // 20,070,400
#define XP_BYTES   (XP_ELEMS * 2)                             // 40,140,800

#define REPACK_BLOCKS (B_ * (H_ + 6))                         // 1120
#define GENW_BLOCKS   (G_ * G_)                               // 64
#define CONV_BLOCKS   (B_ * (H_ / 2))                         // 512

static __device__ __forceinline__ unsigned pack_bf16(float a, float b) {
    union { __bf16 h; unsigned short u; } ua, ub;
    ua.h = (__bf16)a; ub.h = (__bf16)b;
    return (unsigned)ua.u | ((unsigned)ub.u << 16);
}

static __device__ __forceinline__ void dma16(const bf16_t* g, bf16_t* l) {
    __builtin_amdgcn_global_load_lds(
        (const __attribute__((address_space(1))) void*)g,
        (__attribute__((address_space(3))) void*)l, 16, 0, 0);
}

// ---------------------------------------------------------------------------
// Fused prep: blocks [0,1120) repack x -> swizzled bf16 xPad; blocks
// [1120,1184) = (gout,gin) SIREN weight-gen with W3 register reuse.
__global__ void prep(const float* __restrict__ x, bf16_t* __restrict__ xp,
                     const float* __restrict__ thetas,
                     const float* __restrict__ W1, const float* __restrict__ b1,
                     const float* __restrict__ W2, const float* __restrict__ b2,
                     const float* __restrict__ W3, const float* __restrict__ b3,
                     bf16_t* __restrict__ w2out) {
    __shared__ float h1s[49][33];
    __shared__ float h2s[49][33];
    __shared__ float masks[49];
    int tid = threadIdx.x;
    if (blockIdx.x < REPACK_BLOCKS) {
        // ---------------- repack path ----------------
        int blk = blockIdx.x;
        int b = blk / (H_ + 6), hy = blk % (H_ + 6);
        const int4 z4 = make_int4(0, 0, 0, 0);
        if (hy >= H_) {
            int idx = hy - H_;
            int y = (idx < 3) ? idx : idx + 64;   // 0,1,2,67,68,69
            bf16_t* dst = xp + ((size_t)(b * WP_) + y) * WP_ * CH_;
            for (int i = tid; i < WP_ * CH_ / 8; i += 256)
                *reinterpret_cast<int4*>(dst + (size_t)i * 8) = z4;
            return;
        }
        int lane = tid & 63, wv = tid >> 6;
        int r = lane >> 3;          // channel offset within tile / w offset after T
        int t = lane & 7;           // w-chunk
        size_t orow = ((size_t)(b * WP_) + (hy + 3)) * WP_ * CH_;
        for (int it = 0; it < 8; ++it) {
            int c0 = wv * 8 + it * 32;
            const float* src = x + ((size_t)(b * CH_ + c0 + r)) * (H_ * W_)
                                 + (size_t)hy * W_ + t * 8;
            float4 f0 = *reinterpret_cast<const float4*>(src);
            float4 f1 = *reinterpret_cast<const float4*>(src + 4);
            int d0 = (int)pack_bf16(f0.x, f0.y);
            int d1 = (int)pack_bf16(f0.z, f0.w);
            int d2 = (int)pack_bf16(f1.x, f1.y);
            int d3 = (int)pack_bf16(f1.z, f1.w);
            int p0, p1, p2, p3;
            p0 = __shfl_xor(d0, 32); p1 = __shfl_xor(d1, 32);
            p2 = __shfl_xor(d2, 32); p3 = __shfl_xor(d3, 32);
            if ((r & 4) == 0) { d2 = p0; d3 = p1; } else { d0 = p2; d1 = p3; }
            p0 = __shfl_xor(d0, 16); p1 = __shfl_xor(d1, 16);
            p2 = __shfl_xor(d2, 16); p3 = __shfl_xor(d3, 16);
            if ((r & 2) == 0) { d1 = p0; d3 = p2; } else { d0 = p1; d2 = p3; }
            p0 = __shfl_xor(d0, 8); p1 = __shfl_xor(d1, 8);
            p2 = __shfl_xor(d2, 8); p3 = __shfl_xor(d3, 8);
            if ((r & 1) == 0) {
                d0 = (d0 & 0xFFFF) | (p0 << 16);
                d1 = (d1 & 0xFFFF) | (p1 << 16);
                d2 = (d2 & 0xFFFF) | (p2 << 16);
                d3 = (d3 & 0xFFFF) | (p3 << 16);
            } else {
                d0 = (d0 & 0xFFFF0000) | ((unsigned)p0 >> 16);
                d1 = (d1 & 0xFFFF0000) | ((unsigned)p1 >> 16);
                d2 = (d2 & 0xFFFF0000) | ((unsigned)p2 >> 16);
                d3 = (d3 & 0xFFFF0000) | ((unsigned)p3 >> 16);
            }
            int xpos = t * 8 + r + 3;
            int c16 = c0 >> 3;
            int pp = c16 ^ (xpos & 7);       // swizzled chunk position
            int4 v = make_int4(d0, d1, d2, d3);
            *reinterpret_cast<int4*>(xp + orow + (size_t)xpos * CH_ + pp * 8) = v;
        }
        if (tid < 192) {   // zero w-border cols {0,1,2,67,68,69}
            int col = tid >> 5, cg = tid & 31;
            int xx = (col < 3) ? col : col + 64;
            *reinterpret_cast<int4*>(xp + orow + (size_t)xx * CH_ + cg * 8) = z4;
        }
        return;
    }
    // ---------------- gen_w path: block = (gout, gin) ----------------
    int blk = blockIdx.x - REPACK_BLOCKS;
    int gin = blk & 7, gout = blk >> 3;
    const float TWO_PI = 6.283185307179586f;
    const float PI_F   = 3.14159265358979323846f;
    float th_o = thetas[gout], th_i = thetas[gin];
    float d = fmodf(th_i - th_o, TWO_PI);
    if (d < 0.0f) d += TWO_PI;
    float ag = d / PI_F - 1.0f;
    float ct = cosf(-th_o), st = sinf(-th_o);

    if (tid < 196) {
        int p = tid >> 2, q = tid & 3;       // tap, j-octet
        int ky = p / 7, kx = p % 7;
        float yy = (float)(ky - 3) / 3.0f;
        float xx = (float)(kx - 3) / 3.0f;
        float r0 = ct * yy - st * xx;
        float r1 = st * yy + ct * xx;
        if (q == 0)   // radius-1 points INCLUDED (fp32 ref); next r^2 = 10/9
            masks[p] = (r0 * r0 + r1 * r1 <= 1.00001f) ? 1.0f : 0.0f;
        #pragma unroll
        for (int jo = 0; jo < 8; ++jo) {
            int j = q * 8 + jo;
            float a = r0 * W1[j] + r1 * W1[32 + j] + ag * W1[64 + j] + b1[j];
            h1s[p][j] = __sinf(10.0f * a);
        }
    }
    __syncthreads();
    if (tid < 196) {
        int p = tid >> 2, q = tid & 3;
        #pragma unroll
        for (int jo = 0; jo < 8; ++jo) {
            int j = q * 8 + jo;
            float a = b2[j];
            #pragma unroll
            for (int i = 0; i < HID_; ++i) a += h1s[p][i] * W2[i * HID_ + j];
            h2s[p][j] = __sinf(10.0f * a);
        }
    }
    __syncthreads();
    for (int rep = 0; rep < 4; ++rep) {
        int o = rep * 256 + tid;             // cout*32 + cin
        float w3c[HID_];
        #pragma unroll
        for (int i = 0; i < HID_; ++i) w3c[i] = W3[i * 1024 + o];
        float bb = b3[o];
        int cout = o >> 5, cin = o & 31;
        int k = cin * G_ + gin;
        int n = gout * COUT_ + cout;
        int kc = k >> 5, hi = (k >> 3) & 3, jj = k & 7;
        bf16_t* dst = w2out + (((size_t)kc * 4 + hi) * 256 + n) * 8 + jj;
        for (int p = 0; p < 49; ++p) {
            float a = bb;
            #pragma unroll
            for (int i = 0; i < HID_; ++i) a += h2s[p][i] * w3c[i];
            a *= masks[p];
            dst[(size_t)p * (8 * 4 * 256 * 8)] = (bf16_t)a;
        }
    }
}

// ---------------------------------------------------------------------------
// Conv: implicit GEMM, block = (b, h-pair): M=128 (2 output rows x 64 w),
// N=256, K=49*256.  8 waves: wave = (m-half, n-strip).  Two-slot LDS ring
// keyed by row parity; after the first two rows, each ky stages ONE new row.
// Halves per-block B(w2) L2 traffic vs M=64 and doubles MFMA per barrier.
__launch_bounds__(512, 4)
__global__ void conv_mfma(const bf16_t* __restrict__ xp,
                          const bf16_t* __restrict__ w2,
                          const float* __restrict__ bias,
                          float* __restrict__ out) {
    __shared__ __align__(16) bf16_t lds[2][WP_ * CH_];   // 71,680 B
    int blk = blockIdx.x;             // b*32 + hpair
    int b = blk >> 5, h0 = (blk & 31) << 1;
    int tid = threadIdx.x;
    int wv = tid >> 6, lane = tid & 63;
    int m = wv >> 2, ns = wv & 3;     // m-half, n-strip
    int lm = lane & 15, lq = lane >> 4;

    f32x4 acc[4][4];
    #pragma unroll
    for (int i = 0; i < 4; ++i)
        #pragma unroll
        for (int j = 0; j < 4; ++j) {
            f32x4 z = {0.0f, 0.0f, 0.0f, 0.0f};
            acc[i][j] = z;
        }

    const bf16_t* rows = xp + (((size_t)(b * WP_) + h0) * WP_) * CH_;
    // init: stage rows h0 (slot0) and h0+1 (slot1) = 70 chunks of 1KB
    for (int c = wv; c < 70; c += 8)
        dma16(rows + (size_t)c * 512 + lane * 8, &lds[0][0] + c * 512);
    __syncthreads();

    for (int ky = 0; ky < KS_; ++ky) {
        // wave's A row = h0 + m + ky, lives in slot (m+ky)&1
        const bf16_t* slot = &lds[(m + ky) & 1][0];
        #pragma unroll 1
        for (int kx = 0; kx < KS_; ++kx) {
            int tap = ky * KS_ + kx;
            const bf16_t* wbase = w2 + ((size_t)(tap * 32 + lq) * 256 + (ns * 64 + lm)) * 8;
            #pragma unroll 1
            for (int kc = 0; kc < 8; ++kc) {
                const bf16_t* wp = wbase + (size_t)kc * (4 * 256 * 8);
                bf16x8 bfrag[4];
                #pragma unroll
                for (int nt = 0; nt < 4; ++nt)
                    bfrag[nt] = *reinterpret_cast<const bf16x8*>(wp + nt * (16 * 8));
                bf16x8 afrag[4];
                #pragma unroll
                for (int mt = 0; mt < 4; ++mt) {
                    int xr = mt * 16 + lm + kx;
                    int pp = (kc * 4 + lq) ^ (xr & 7);   // un-swizzle
                    afrag[mt] = *reinterpret_cast<const bf16x8*>(&slot[xr * CH_ + pp * 8]);
                }
                #pragma unroll
                for (int mt = 0; mt < 4; ++mt)
                    #pragma unroll
                    for (int nt = 0; nt < 4; ++nt)
                        acc[mt][nt] = __builtin_amdgcn_mfma_f32_16x16x32_bf16(
                            afrag[mt], bfrag[nt], acc[mt][nt], 0, 0, 0);
            }
        }
        if (ky < KS_ - 1) {
            __syncthreads();   // all waves done reading slot ky&1
            // overwrite slot ky&1 with row h0+ky+2 (same parity)
            bf16_t* dstslot = &lds[ky & 1][0];
            const bf16_t* src = rows + (size_t)(ky + 2) * WP_ * CH_;
            for (int c = wv; c < 35; c += 8)
                dma16(src + (size_t)c * 512 + lane * 8, dstslot + c * 512);
            __syncthreads();   // drain DMA
        }
    }

    // epilogue: D row = lq*4 + reg (w offset), col = lm (n offset)
    int h = h0 + m;
    #pragma unroll
    for (int mt = 0; mt < 4; ++mt) {
        int wq = mt * 16 + lq * 4;
        #pragma unroll
        for (int nt = 0; nt < 4; ++nt) {
            int n = ns * 64 + nt * 16 + lm;
            int gout = n >> 5, cout = n & 31;
            float bv = bias[cout];
            f32x4 v = acc[mt][nt];
            v[0] += bv; v[1] += bv; v[2] += bv; v[3] += bv;
            float* po = out + (((size_t)(b * COUT_ + cout) * G_ + gout) * (H_ * W_)
                               + h * W_ + wq);
            *reinterpret_cast<f32x4*>(po) = v;
        }
    }
}

// ---------------------------------------------------------------------------
extern "C" void kernel_launch(void* const* d_in, const int* in_sizes, int n_in,
                              void* d_out, int out_size, void* d_ws, size_t ws_size,
                              hipStream_t stream) {
    const float* x      = (const float*)d_in[0];
    const float* thetas = (const float*)d_in[1];
    const float* W1     = (const float*)d_in[2];
    const float* b1     = (const float*)d_in[3];
    const float* W2     = (const float*)d_in[4];
    const float* b2     = (const float*)d_in[5];
    const float* W3     = (const float*)d_in[6];
    const float* b3     = (const float*)d_in[7];
    const float* bias   = (const float*)d_in[8];
    float* out = (float*)d_out;

    bf16_t* xp = (bf16_t*)d_ws;
    bf16_t* w2 = (bf16_t*)((char*)d_ws + XP_BYTES);

    hipLaunchKernelGGL(prep, dim3(REPACK_BLOCKS + GENW_BLOCKS), dim3(256), 0, stream,
                       x, xp, thetas, W1, b1, W2, b2, W3, b3, w2);
    hipLaunchKernelGGL(conv_mfma, dim3(CONV_BLOCKS), dim3(512), 0, stream,
                       xp, w2, bias, out);
}

// Round 5
// 474.561 us; speedup vs baseline: 1.3124x; 1.0535x over previous
//
#include <hip/hip_runtime.h>
#include <math.h>

typedef __bf16 bf16_t;
typedef __bf16 bf16x8 __attribute__((ext_vector_type(8)));
typedef float  f32x4  __attribute__((ext_vector_type(4)));

#define B_    16
#define CIN_  32
#define COUT_ 32
#define G_    8
#define CH_   256      // Cin*Gin = K channels per tap
#define H_    64
#define W_    64
#define HID_  32
#define KS_   7
#define PAD_  3
#define WP_   70       // W + 2*PAD

// xp layout: [B][y(70)][c16(32)][x(70)][8ch]  (chunk-major rows).
// Repack stores are contiguous per wave; conv row image is linear (DMA-able)
// and A-fragment ds_read_b128 is naturally conflict-free (16 lanes read one
// contiguous 256B run per chunk).
#define ROW_ELEMS  (WP_ * CH_)                                // 17,920 per row
#define XP_ELEMS   ((size_t)B_ * WP_ * ROW_ELEMS)             // 20,070,400
#define XP_BYTES   (XP_ELEMS * 2)                             // 40,140,800

#define REPACK_BLOCKS (B_ * (H_ + 6))                         // 1120
#define GENW_BLOCKS   (G_ * G_)                               // 64
#define CONV_BLOCKS   (B_ * (H_ / 2))                         // 512 = 2/CU exactly

static __device__ __forceinline__ unsigned pack_bf16(float a, float b) {
    union { __bf16 h; unsigned short u; } ua, ub;
    ua.h = (__bf16)a; ub.h = (__bf16)b;
    return (unsigned)ua.u | ((unsigned)ub.u << 16);
}

static __device__ __forceinline__ void dma16(const bf16_t* g, bf16_t* l) {
    __builtin_amdgcn_global_load_lds(
        (const __attribute__((address_space(1))) void*)g,
        (__attribute__((address_space(3))) void*)l, 16, 0, 0);
}

// ---------------------------------------------------------------------------
// Fused prep: blocks [0,1120) repack x -> chunk-major bf16 xPad; blocks
// [1120,1184) = (gout,gin) SIREN weight-gen with W3 register reuse.
__global__ void prep(const float* __restrict__ x, bf16_t* __restrict__ xp,
                     const float* __restrict__ thetas,
                     const float* __restrict__ W1, const float* __restrict__ b1,
                     const float* __restrict__ W2, const float* __restrict__ b2,
                     const float* __restrict__ W3, const float* __restrict__ b3,
                     bf16_t* __restrict__ w2out) {
    __shared__ float h1s[49][33];
    __shared__ float h2s[49][33];
    __shared__ float masks[49];
    int tid = threadIdx.x;
    if (blockIdx.x < REPACK_BLOCKS) {
        // ---------------- repack path ----------------
        int blk = blockIdx.x;
        int b = blk / (H_ + 6), hy = blk % (H_ + 6);
        const int4 z4 = make_int4(0, 0, 0, 0);
        if (hy >= H_) {
            int idx = hy - H_;
            int y = (idx < 3) ? idx : idx + 64;   // 0,1,2,67,68,69
            bf16_t* dst = xp + ((size_t)(b * WP_) + y) * ROW_ELEMS;
            for (int i = tid; i < ROW_ELEMS / 8; i += 256)
                *reinterpret_cast<int4*>(dst + (size_t)i * 8) = z4;
            return;
        }
        int lane = tid & 63, wv = tid >> 6;
        int r = lane >> 3;          // channel offset in tile -> w offset after T
        int t = lane & 7;           // w-chunk
        size_t orow = ((size_t)(b * WP_) + (hy + 3)) * ROW_ELEMS;
        for (int it = 0; it < 8; ++it) {
            int c0 = wv * 8 + it * 32;
            const float* src = x + ((size_t)(b * CH_ + c0 + r)) * (H_ * W_)
                                 + (size_t)hy * W_ + t * 8;
            float4 f0 = *reinterpret_cast<const float4*>(src);
            float4 f1 = *reinterpret_cast<const float4*>(src + 4);
            int d0 = (int)pack_bf16(f0.x, f0.y);
            int d1 = (int)pack_bf16(f0.z, f0.w);
            int d2 = (int)pack_bf16(f1.x, f1.y);
            int d3 = (int)pack_bf16(f1.z, f1.w);
            int p0, p1, p2, p3;
            p0 = __shfl_xor(d0, 32); p1 = __shfl_xor(d1, 32);
            p2 = __shfl_xor(d2, 32); p3 = __shfl_xor(d3, 32);
            if ((r & 4) == 0) { d2 = p0; d3 = p1; } else { d0 = p2; d1 = p3; }
            p0 = __shfl_xor(d0, 16); p1 = __shfl_xor(d1, 16);
            p2 = __shfl_xor(d2, 16); p3 = __shfl_xor(d3, 16);
            if ((r & 2) == 0) { d1 = p0; d3 = p2; } else { d0 = p1; d2 = p3; }
            p0 = __shfl_xor(d0, 8); p1 = __shfl_xor(d1, 8);
            p2 = __shfl_xor(d2, 8); p3 = __shfl_xor(d3, 8);
            if ((r & 1) == 0) {
                d0 = (d0 & 0xFFFF) | (p0 << 16);
                d1 = (d1 & 0xFFFF) | (p1 << 16);
                d2 = (d2 & 0xFFFF) | (p2 << 16);
                d3 = (d3 & 0xFFFF) | (p3 << 16);
            } else {
                d0 = (d0 & 0xFFFF0000) | ((unsigned)p0 >> 16);
                d1 = (d1 & 0xFFFF0000) | ((unsigned)p1 >> 16);
                d2 = (d2 & 0xFFFF0000) | ((unsigned)p2 >> 16);
                d3 = (d3 & 0xFFFF0000) | ((unsigned)p3 >> 16);
            }
            int xpos = t * 8 + r + 3;
            int c16 = c0 >> 3;
            int4 v = make_int4(d0, d1, d2, d3);
            // chunk-major: wave's 64 stores cover one contiguous 1024B run
            *reinterpret_cast<int4*>(xp + orow + ((size_t)c16 * WP_ + xpos) * 8) = v;
        }
        if (tid < 192) {   // zero w-border cols {0,1,2,67,68,69} in every chunk
            int col = tid >> 5, cg = tid & 31;
            int xx = (col < 3) ? col : col + 64;
            *reinterpret_cast<int4*>(xp + orow + ((size_t)cg * WP_ + xx) * 8) = z4;
        }
        return;
    }
    // ---------------- gen_w path: block = (gout, gin) ----------------
    int blk = blockIdx.x - REPACK_BLOCKS;
    int gin = blk & 7, gout = blk >> 3;
    const float TWO_PI = 6.283185307179586f;
    const float PI_F   = 3.14159265358979323846f;
    float th_o = thetas[gout], th_i = thetas[gin];
    float d = fmodf(th_i - th_o, TWO_PI);
    if (d < 0.0f) d += TWO_PI;
    float ag = d / PI_F - 1.0f;
    float ct = cosf(-th_o), st = sinf(-th_o);

    if (tid < 196) {
        int p = tid >> 2, q = tid & 3;       // tap, j-octet
        int ky = p / 7, kx = p % 7;
        float yy = (float)(ky - 3) / 3.0f;
        float xx = (float)(kx - 3) / 3.0f;
        float r0 = ct * yy - st * xx;
        float r1 = st * yy + ct * xx;
        if (q == 0)   // radius-1 points INCLUDED (fp32 ref); next r^2 = 10/9
            masks[p] = (r0 * r0 + r1 * r1 <= 1.00001f) ? 1.0f : 0.0f;
        #pragma unroll
        for (int jo = 0; jo < 8; ++jo) {
            int j = q * 8 + jo;
            float a = r0 * W1[j] + r1 * W1[32 + j] + ag * W1[64 + j] + b1[j];
            h1s[p][j] = __sinf(10.0f * a);
        }
    }
    __syncthreads();
    if (tid < 196) {
        int p = tid >> 2, q = tid & 3;
        #pragma unroll
        for (int jo = 0; jo < 8; ++jo) {
            int j = q * 8 + jo;
            float a = b2[j];
            #pragma unroll
            for (int i = 0; i < HID_; ++i) a += h1s[p][i] * W2[i * HID_ + j];
            h2s[p][j] = __sinf(10.0f * a);
        }
    }
    __syncthreads();
    for (int rep = 0; rep < 4; ++rep) {
        int o = rep * 256 + tid;             // cout*32 + cin
        float w3c[HID_];
        #pragma unroll
        for (int i = 0; i < HID_; ++i) w3c[i] = W3[i * 1024 + o];
        float bb = b3[o];
        int cout = o >> 5, cin = o & 31;
        int k = cin * G_ + gin;
        int n = gout * COUT_ + cout;
        int kc = k >> 5, hi = (k >> 3) & 3, jj = k & 7;
        bf16_t* dst = w2out + (((size_t)kc * 4 + hi) * 256 + n) * 8 + jj;
        for (int p = 0; p < 49; ++p) {
            float a = bb;
            #pragma unroll
            for (int i = 0; i < HID_; ++i) a += h2s[p][i] * w3c[i];
            a *= masks[p];
            dst[(size_t)p * (8 * 4 * 256 * 8)] = (bf16_t)a;
        }
    }
}

// ---------------------------------------------------------------------------
// Conv: implicit GEMM, block = (b, h-pair). 4 waves, wave = one 64-wide
// N-strip covering the FULL M=128 (both output rows): acc[8][4].  This
// halves B-load request bytes per MFMA (the R4 bottleneck: 64 B/cyc/CU
// request demand vs ~56 B/cyc L2 service).  Two-slot LDS ring by row parity.
__launch_bounds__(256, 2)
__global__ void conv_mfma(const bf16_t* __restrict__ xp,
                          const bf16_t* __restrict__ w2,
                          const float* __restrict__ bias,
                          float* __restrict__ out) {
    __shared__ __align__(16) bf16_t lds[2][ROW_ELEMS];   // 71,680 B
    int blk = blockIdx.x;             // b*32 + hpair
    int b = blk >> 5, h0 = (blk & 31) << 1;
    int tid = threadIdx.x;
    int ns = tid >> 6, lane = tid & 63;
    int lm = lane & 15, lq = lane >> 4;

    f32x4 acc[8][4];
    #pragma unroll
    for (int i = 0; i < 8; ++i)
        #pragma unroll
        for (int j = 0; j < 4; ++j) {
            f32x4 z = {0.0f, 0.0f, 0.0f, 0.0f};
            acc[i][j] = z;
        }

    const bf16_t* rows = xp + (((size_t)(b * WP_) + h0)) * ROW_ELEMS;
    // init: stage rows h0 (slot0) and h0+1 (slot1): 70 chunks of 1KB, linear
    for (int c = ns; c < 70; c += 4)
        dma16(rows + (size_t)c * 512 + lane * 8, &lds[0][0] + c * 512);
    __syncthreads();

    for (int ky = 0; ky < KS_; ++ky) {
        const bf16_t* slotA = &lds[ky & 1][0];        // image row h0+ky   (mt 0-3)
        const bf16_t* slotB = &lds[(ky + 1) & 1][0];  // image row h0+ky+1 (mt 4-7)
        #pragma unroll 1
        for (int kx = 0; kx < KS_; ++kx) {
            int tap = ky * KS_ + kx;
            const bf16_t* wbase = w2 + ((size_t)(tap * 32 + lq) * 256 + (ns * 64 + lm)) * 8;
            #pragma unroll 2
            for (int kc = 0; kc < 8; ++kc) {
                const bf16_t* wp = wbase + (size_t)kc * (4 * 256 * 8);
                bf16x8 bfrag[4];
                #pragma unroll
                for (int nt = 0; nt < 4; ++nt)
                    bfrag[nt] = *reinterpret_cast<const bf16x8*>(wp + nt * (16 * 8));
                int cb = (kc * 4 + lq) * WP_;         // chunk-major base
                bf16x8 afrag[8];
                #pragma unroll
                for (int mt = 0; mt < 4; ++mt) {
                    int xr = mt * 16 + lm + kx;
                    afrag[mt]     = *reinterpret_cast<const bf16x8*>(&slotA[(cb + xr) * 8]);
                    afrag[mt + 4] = *reinterpret_cast<const bf16x8*>(&slotB[(cb + xr) * 8]);
                }
                #pragma unroll
                for (int mt = 0; mt < 8; ++mt)
                    #pragma unroll
                    for (int nt = 0; nt < 4; ++nt)
                        acc[mt][nt] = __builtin_amdgcn_mfma_f32_16x16x32_bf16(
                            afrag[mt], bfrag[nt], acc[mt][nt], 0, 0, 0);
            }
        }
        if (ky < KS_ - 1) {
            __syncthreads();   // all waves done with row h0+ky (slot ky&1)
            bf16_t* dstslot = &lds[ky & 1][0];
            const bf16_t* src = rows + (size_t)(ky + 2) * ROW_ELEMS;
            for (int c = ns; c < 35; c += 4)
                dma16(src + (size_t)c * 512 + lane * 8, dstslot + c * 512);
            __syncthreads();   // drain DMA
        }
    }

    // epilogue: D row = lq*4 + reg (w offset), col = lm (n offset)
    #pragma unroll
    for (int mt = 0; mt < 8; ++mt) {
        int h = h0 + (mt >> 2);
        int wq = (mt & 3) * 16 + lq * 4;
        #pragma unroll
        for (int nt = 0; nt < 4; ++nt) {
            int n = ns * 64 + nt * 16 + lm;
            int gout = n >> 5, cout = n & 31;
            float bv = bias[cout];
            f32x4 v = acc[mt][nt];
            v[0] += bv; v[1] += bv; v[2] += bv; v[3] += bv;
            float* po = out + (((size_t)(b * COUT_ + cout) * G_ + gout) * (H_ * W_)
                               + h * W_ + wq);
            *reinterpret_cast<f32x4*>(po) = v;
        }
    }
}

// ---------------------------------------------------------------------------
extern "C" void kernel_launch(void* const* d_in, const int* in_sizes, int n_in,
                              void* d_out, int out_size, void* d_ws, size_t ws_size,
                              hipStream_t stream) {
    const float* x      = (const float*)d_in[0];
    const float* thetas = (const float*)d_in[1];
    const float* W1     = (const float*)d_in[2];
    const float* b1     = (const float*)d_in[3];
    const float* W2     = (const float*)d_in[4];
    const float* b2     = (const float*)d_in[5];
    const float* W3     = (const float*)d_in[6];
    const float* b3     = (const float*)d_in[7];
    const float* bias   = (const float*)d_in[8];
    float* out = (float*)d_out;

    bf16_t* xp = (bf16_t*)d_ws;
    bf16_t* w2 = (bf16_t*)((char*)d_ws + XP_BYTES);

    hipLaunchKernelGGL(prep, dim3(REPACK_BLOCKS + GENW_BLOCKS), dim3(256), 0, stream,
                       x, xp, thetas, W1, b1, W2, b2, W3, b3, w2);
    hipLaunchKernelGGL(conv_mfma, dim3(CONV_BLOCKS), dim3(256), 0, stream,
                       xp, w2, bias, out);
}